// Round 1
// baseline (14141.389 us; speedup 1.0000x reference)
//
#include <hip/hip_runtime.h>

// NeuralCDE: B=64,T=256,C=16,S=64,H=128. fp32 recursion (f16 decorrelates).
// R13: VGPR stuck at 128 across 6 rounds = allocator targeting default
// 4 waves/EU (512/4=128); __launch_bounds__(512,1) lowers to its own
// amdgpu-waves-per-eu attr and clobbers the explicit (2,2). Pivot per R11's
// own signature: (1) three attribute variants of one body — wpe-only,
// num_vgpr(256), and the old combo as fallback — arbitrated at first launch
// via hipFuncGetAttributes (min localSizeBytes = no scratch, then max
// numRegs); (2) one-time W2 transpose into d_ws so the per-stage streamed
// cols 72..89 read as lane-contiguous float2 (wave = 512B contiguous/col,
// 4 lines/inst vs 64 before) and the LDS fill coalesces.
// Budget at 256: fixed ~22 + W0/W1 48 + W2 pins 144 + stream 36 + temps ~10
// = ~260 -> at most a couple cold spills; at 128 nothing regresses vs R11.
// SIGNATURE next round: VGPR_Count ~250 => granted (expect ~2.6-3.6 ms);
// 128 => all variants capped, streaming-coalescing only (~5.8-6.3 ms).

typedef float float4v __attribute__((ext_vector_type(4)));
typedef float float2v __attribute__((ext_vector_type(2)));

__device__ __forceinline__ float dot4(float4v a, float4v b) {
  return a.x * b.x + a.y * b.y + a.z * b.z + a.w * b.w;
}

__device__ __forceinline__ float softplus_fast(float x) {
  float z = __expf(-fabsf(x));
  return fmaxf(x, 0.f) + __logf(1.f + z);
}

__device__ __forceinline__ float tanh_hw(float x) {
  float e = __expf(2.f * x);  // inf-safe
  return 1.f - 2.f * __builtin_amdgcn_rcpf(e + 1.f);
}

__device__ __forceinline__ void cde_body(
    const float* __restrict__ xs,
    const float* __restrict__ icw0, const float* __restrict__ icb0,
    const float* __restrict__ icw1, const float* __restrict__ icb1,
    const float* __restrict__ icw2, const float* __restrict__ icb2,
    const float* __restrict__ vfw0, const float* __restrict__ vfb0,
    const float* __restrict__ vfw1, const float* __restrict__ vfb1,
    const float* __restrict__ vfw2, const float* __restrict__ vfb2,
    const float* __restrict__ w2t, float* __restrict__ ybuf) {
  constexpr float Ac[6][5] = {
      {0.f, 0.f, 0.f, 0.f, 0.f},
      {0.161f, 0.f, 0.f, 0.f, 0.f},
      {-0.008480655492356989f, 0.335480655492357f, 0.f, 0.f, 0.f},
      {2.8971530571054935f, -6.359448489975075f, 4.3622954328695815f, 0.f, 0.f},
      {5.325864828439257f, -11.748883564062828f, 7.4955393428898365f,
       -0.09249506636175525f, 0.f},
      {5.86145544294642f, -12.92096931784711f, 8.159367898576159f,
       -0.071584973281401f, -0.028269050394068383f}};
  constexpr float SCv[6] = {0.f, 0.161f, 0.327f, 0.9f, 0.9800255409045097f, 1.f};
  constexpr float BWv[6] = {0.09646076681806523f, 0.01f, 0.4798896504144996f,
                            1.379008574103742f, -3.290069515436081f,
                            2.324710524099774f};

  const int tid = threadIdx.x;
  const int w = tid >> 6, l = tid & 63;
  const int b = blockIdx.x;  // one block per batch element

  __shared__ float sW2t[38][1024];              // W2 cols 90..127 col-major
  __shared__ __align__(16) float sYtw[8][64];   // wave-private stage inputs
  __shared__ __align__(16) float sH1[128];
  __shared__ __align__(16) float sH2[128];
  __shared__ float sK[6][64];

  // ---- one-time: LDS W2 tail columns (coalesced when transpose exists) ----
  if (w2t) {
    for (int i = tid; i < 38 * 1024; i += 512) {
      int k = i >> 10, r = i & 1023;
      sW2t[k][r] = w2t[(size_t)(90 + k) * 1024 + r];
    }
  } else {
    for (int i = tid; i < 38 * 1024; i += 512) {
      int k = i >> 10, r = i & 1023;
      sW2t[k][r] = vfw2[(size_t)r * 128 + 90 + k];
    }
  }

  // ---- one-time: resident weights, pinned (cols 0..71 of rows r0,r1) ----
  const int r0 = tid * 2, r1 = r0 + 1;
  float w2a[72], w2b[72];
  {
    const float4v* p0 = (const float4v*)(vfw2 + (size_t)r0 * 128);
    const float4v* p1 = (const float4v*)(vfw2 + (size_t)r1 * 128);
#pragma unroll
    for (int kk = 0; kk < 18; ++kk) {
      float4v a = p0[kk], c = p1[kk];
      w2a[4 * kk + 0] = a.x; w2a[4 * kk + 1] = a.y;
      w2a[4 * kk + 2] = a.z; w2a[4 * kk + 3] = a.w;
      w2b[4 * kk + 0] = c.x; w2b[4 * kk + 1] = c.y;
      w2b[4 * kk + 2] = c.z; w2b[4 * kk + 3] = c.w;
    }
  }
#pragma unroll
  for (int kk = 0; kk < 72; ++kk)
    asm volatile("" : "+v"(w2a[kk]), "+v"(w2b[kk]));

  const int ii = tid >> 2, q4 = tid & 3;  // h1/h2: 4 lanes per output
  float w0r[16], w1r[32];
  {
    const float4v* p = (const float4v*)(vfw0 + (size_t)ii * 64 + q4 * 16);
#pragma unroll
    for (int kk = 0; kk < 4; ++kk) {
      float4v a = p[kk];
      w0r[4 * kk] = a.x; w0r[4 * kk + 1] = a.y;
      w0r[4 * kk + 2] = a.z; w0r[4 * kk + 3] = a.w;
    }
  }
  {
    const float4v* p = (const float4v*)(vfw1 + (size_t)ii * 128 + q4 * 32);
#pragma unroll
    for (int kk = 0; kk < 8; ++kk) {
      float4v a = p[kk];
      w1r[4 * kk] = a.x; w1r[4 * kk + 1] = a.y;
      w1r[4 * kk + 2] = a.z; w1r[4 * kk + 3] = a.w;
    }
  }
#pragma unroll
  for (int kk = 0; kk < 16; ++kk) asm volatile("" : "+v"(w0r[kk]));
#pragma unroll
  for (int kk = 0; kk < 32; ++kk) asm volatile("" : "+v"(w1r[kk]));

  const float b2r0 = vfb2[r0], b2r1 = vfb2[r1];
  const int c0 = (2 * l) & 15;  // even dx channel of row r0; r1 -> c0+1
  const float b0i = vfb0[ii], b1i = vfb1[ii];

  const float* Xb = xs + (size_t)b * 4096;
  float* yb = ybuf + (size_t)b * 16384;

  __syncthreads();

  // ---- initial condition MLP (one-time; sTA := sK[0..1], sTB := sH1) ----
  float* sTA = &sK[0][0];
  float* sTB = sH1;
  if (tid < 128) {
    float a = icb0[tid];
    const float* wr = icw0 + tid * 16;
#pragma unroll
    for (int k = 0; k < 16; ++k) a += wr[k] * Xb[k];
    sTA[tid] = softplus_fast(a);
  }
  __syncthreads();
  if (tid < 128) {
    float a = icb1[tid];
    const float* wr = icw1 + tid * 128;
    for (int k = 0; k < 128; ++k) a += wr[k] * sTA[k];
    sTB[tid] = softplus_fast(a);
  }
  __syncthreads();
  if (tid < 64) {
    float a = icb2[tid];
    const float* wr = icw2 + tid * 128;
    for (int k = 0; k < 128; ++k) a += wr[k] * sTB[k];
    sH2[tid] = a;  // temp broadcast slot
  }
  __syncthreads();
  float yreg = sH2[l];  // every wave holds y[l]
  if (w == 0) yb[l] = yreg;

  const float hstep = 1.f / 255.f;
  const float invh = 255.f;

#pragma unroll 1
  for (int t = 0; t < 255; ++t) {
    // per-lane x-channel pair (c0, c0+1): j-invariant dXdt basis in regs
    float2v xt = *(const float2v*)(Xb + t * 16 + c0);
    float2v xt1 = *(const float2v*)(Xb + (t + 1) * 16 + c0);
    float2v xtm = xt;
    if (t != 0) xtm = *(const float2v*)(Xb + (t - 1) * 16 + c0);
    const float u0 = xt.x - xt1.x, u1 = xt.y - xt1.y;       // (xi - xip1)
    const float dp0 = (xt1.x - xt.x) * invh;                 // dfull[t+1]
    const float dp1 = (xt1.y - xt.y) * invh;
    float di0 = (t == 0) ? dp0 : (xt.x - xtm.x) * invh;      // dfull[t]
    float di1 = (t == 0) ? dp1 : (xt.y - xtm.y) * invh;
#pragma unroll 1
    for (int j = 0; j < 6; ++j) {
      // ---- streamed W2 cols 72..89 (consumed in k-phase) ----
      // st[c].x = W2[r0][72+c], st[c].y = W2[r1][72+c]
      float2v st[18];
      if (w2t) {
        const float* sbase = w2t + (size_t)72 * 1024 + r0;  // col-major
#pragma unroll
        for (int c = 0; c < 18; ++c)
          st[c] = *(const float2v*)(sbase + (size_t)c * 1024);
      } else {
        const float* wr0 = vfw2 + (size_t)r0 * 128;
        const float* wr1 = vfw2 + (size_t)r1 * 128;
#pragma unroll
        for (int c = 0; c < 18; ++c) {
          st[c].x = wr0[72 + c];
          st[c].y = wr1[72 + c];
        }
      }
      // ---- stage input y_j: every wave, per-lane, wave-private buffer ----
      {
        float yt = yreg;
#pragma unroll
        for (int m = 0; m < 5; ++m)
          if (m < j) yt += hstep * Ac[j][m] * sK[m][l];
        sYtw[w][l] = yt;
      }
      asm volatile("s_waitcnt lgkmcnt(0)" ::: "memory");  // in-wave only
      // ---- dXdt(sc_j) in registers ----
      const float sc = SCv[j], s2 = sc * sc;
      const float a1 = (6.f * s2 - 6.f * sc) * invh;
      const float a2 = 3.f * s2 - 4.f * sc + 1.f;
      const float a3 = 3.f * s2 - 2.f * sc;
      const float dx0 = a1 * u0 + a2 * di0 + a3 * dp0;
      const float dx1 = a1 * u1 + a2 * di1 + a3 * dp1;
      // ---- h1 = softplus(W0 @ y + b0) ----
      {
        const float4v* yv = (const float4v*)(&sYtw[w][0] + q4 * 16);
        float4v y0 = yv[0], y1 = yv[1], y2 = yv[2], y3 = yv[3];
        float s = w0r[0] * y0.x + w0r[1] * y0.y + w0r[2] * y0.z +
                  w0r[3] * y0.w + w0r[4] * y1.x + w0r[5] * y1.y +
                  w0r[6] * y1.z + w0r[7] * y1.w + w0r[8] * y2.x +
                  w0r[9] * y2.y + w0r[10] * y2.z + w0r[11] * y2.w +
                  w0r[12] * y3.x + w0r[13] * y3.y + w0r[14] * y3.z +
                  w0r[15] * y3.w;
        s += __shfl_xor(s, 1);
        s += __shfl_xor(s, 2);
        if (q4 == 0) sH1[ii] = softplus_fast(s + b0i);
      }
      __syncthreads();
      // ---- h2 = softplus(W1 @ h1 + b1) ----
      {
        const float4v* hv = (const float4v*)(sH1 + q4 * 32);
        float s = 0.f;
#pragma unroll
        for (int kk = 0; kk < 8; ++kk) {
          float4v h = hv[kk];
          s += w1r[4 * kk] * h.x + w1r[4 * kk + 1] * h.y +
               w1r[4 * kk + 2] * h.z + w1r[4 * kk + 3] * h.w;
        }
        s += __shfl_xor(s, 1);
        s += __shfl_xor(s, 2);
        if (q4 == 0) sH2[ii] = softplus_fast(s + b1i);
      }
      __syncthreads();
      // ---- k: rows r0,r1 of A = tanh(W2 h2 + b2), * dx, reduce over c ----
      {
        const float4v* hv = (const float4v*)sH2;
        float s0 = 0.f, s1 = 0.f;
#pragma unroll
        for (int kk = 0; kk < 18; ++kk) {  // pinned cols 0..71
          float4v h = hv[kk];
          s0 += w2a[4 * kk] * h.x + w2a[4 * kk + 1] * h.y +
                w2a[4 * kk + 2] * h.z + w2a[4 * kk + 3] * h.w;
          s1 += w2b[4 * kk] * h.x + w2b[4 * kk + 1] * h.y +
                w2b[4 * kk + 2] * h.z + w2b[4 * kk + 3] * h.w;
        }
        {  // streamed cols 72..89
          float4v h0 = hv[18], h1 = hv[19], h2f = hv[20], h3 = hv[21];
          float2v h4 = *(const float2v*)(sH2 + 88);
          s0 += st[0].x * h0.x + st[1].x * h0.y + st[2].x * h0.z +
                st[3].x * h0.w + st[4].x * h1.x + st[5].x * h1.y +
                st[6].x * h1.z + st[7].x * h1.w + st[8].x * h2f.x +
                st[9].x * h2f.y + st[10].x * h2f.z + st[11].x * h2f.w +
                st[12].x * h3.x + st[13].x * h3.y + st[14].x * h3.z +
                st[15].x * h3.w + st[16].x * h4.x + st[17].x * h4.y;
          s1 += st[0].y * h0.x + st[1].y * h0.y + st[2].y * h0.z +
                st[3].y * h0.w + st[4].y * h1.x + st[5].y * h1.y +
                st[6].y * h1.z + st[7].y * h1.w + st[8].y * h2f.x +
                st[9].y * h2f.y + st[10].y * h2f.z + st[11].y * h2f.w +
                st[12].y * h3.x + st[13].y * h3.y + st[14].y * h3.z +
                st[15].y * h3.w + st[16].y * h4.x + st[17].y * h4.y;
        }
#pragma unroll 4
        for (int k2 = 0; k2 < 19; ++k2) {  // LDS cols 90..127, pairwise
          float2v hk = *(const float2v*)(sH2 + 90 + 2 * k2);
          float2v wlo = *(const float2v*)&sW2t[2 * k2][r0];
          float2v whi = *(const float2v*)&sW2t[2 * k2 + 1][r0];
          s0 += wlo.x * hk.x + whi.x * hk.y;
          s1 += wlo.y * hk.x + whi.y * hk.y;
        }
        float f = tanh_hw(s0 + b2r0) * dx0 + tanh_hw(s1 + b2r1) * dx1;
        f += __shfl_xor(f, 1);
        f += __shfl_xor(f, 2);
        f += __shfl_xor(f, 4);
        if ((tid & 7) == 0) sK[j][tid >> 3] = f;
      }
      __syncthreads();
    }
    // ---- y_{t+1}: every wave redundantly; wave0 dumps the state ----
    {
      float yn = yreg;
#pragma unroll
      for (int m = 0; m < 6; ++m) yn += hstep * BWv[m] * sK[m][l];
      yreg = yn;
      if (w == 0) yb[(size_t)(t + 1) * 64 + l] = yn;
    }
  }
}

#define CDE_ARGS_DECL \
    const float* __restrict__ xs, \
    const float* __restrict__ icw0, const float* __restrict__ icb0, \
    const float* __restrict__ icw1, const float* __restrict__ icb1, \
    const float* __restrict__ icw2, const float* __restrict__ icb2, \
    const float* __restrict__ vfw0, const float* __restrict__ vfb0, \
    const float* __restrict__ vfw1, const float* __restrict__ vfb1, \
    const float* __restrict__ vfw2, const float* __restrict__ vfb2, \
    const float* __restrict__ w2t, float* __restrict__ ybuf
#define CDE_ARGS_PASS \
    xs, icw0, icb0, icw1, icb1, icw2, icb2, vfw0, vfb0, vfw1, vfb1, vfw2, \
    vfb2, w2t, ybuf

// Variant A: clean waves-per-eu(2,2) request, no __launch_bounds__ to
// clobber it. LDS (160KB -> 1 WG -> 2 waves/EU) makes (2,2) feasible.
__global__ __attribute__((amdgpu_flat_work_group_size(512, 512),
                          amdgpu_waves_per_eu(2, 2)))
void cde_wpe(CDE_ARGS_DECL) { cde_body(CDE_ARGS_PASS); }

// Variant B: direct VGPR-count request.
__global__ __attribute__((amdgpu_flat_work_group_size(512, 512),
                          amdgpu_num_vgpr(256)))
void cde_nvg(CDE_ARGS_DECL) { cde_body(CDE_ARGS_PASS); }

// Variant C: R11's exact attribute combo — known-good 6.5 ms fallback.
__global__ __attribute__((amdgpu_waves_per_eu(2, 2)))
__launch_bounds__(512, 1) void cde_base(CDE_ARGS_DECL) {
  cde_body(CDE_ARGS_PASS);
}

// One-time W2 transpose: w2t[c*1024+r] = vfw2[r*128+c]. Coalesced reads.
__global__ __launch_bounds__(256) void w2t_prep(const float* __restrict__ w2,
                                                float* __restrict__ out) {
  int i = blockIdx.x * 256 + threadIdx.x;  // [0, 131072)
  int r = i >> 7, c = i & 127;
  out[(size_t)c * 1024 + r] = w2[i];
}

// Parallel readout: one thread per (b,t): out6 = y @ ro^T + rob, 6D->SO(3).
__global__ __launch_bounds__(256) void readout(
    const float* __restrict__ ybuf, const float* __restrict__ row,
    const float* __restrict__ rob, float* __restrict__ out) {
  int idx = blockIdx.x * blockDim.x + threadIdx.x;  // b*256+t
  const float* y = ybuf + (size_t)idx * 64;
  float p[6];
#pragma unroll
  for (int o = 0; o < 6; ++o) {
    const float4v* rr = (const float4v*)(row + o * 64);
    const float4v* yv = (const float4v*)y;
    float s = 0.f;
#pragma unroll
    for (int k = 0; k < 16; ++k) s += dot4(rr[k], yv[k]);
    p[o] = s + rob[o];
  }
  float a1x = p[0], a1y = p[1], a1z = p[2];
  float a2x = p[3], a2y = p[4], a2z = p[5];
  float n1 = rsqrtf(a1x * a1x + a1y * a1y + a1z * a1z);
  float b1x = a1x * n1, b1y = a1y * n1, b1z = a1z * n1;
  float d = b1x * a2x + b1y * a2y + b1z * a2z;
  float px = a2x - d * b1x, py = a2y - d * b1y, pz = a2z - d * b1z;
  float n2 = rsqrtf(px * px + py * py + pz * pz);
  float b2x = px * n2, b2y = py * n2, b2z = pz * n2;
  float b3x = b1y * b2z - b1z * b2y;
  float b3y = b1z * b2x - b1x * b2z;
  float b3z = b1x * b2y - b1y * b2x;
  float* o = out + (size_t)idx * 9;
  o[0] = b1x; o[1] = b2x; o[2] = b3x;
  o[3] = b1y; o[4] = b2y; o[5] = b3y;
  o[6] = b1z; o[7] = b2z; o[8] = b3z;
}

extern "C" void kernel_launch(void* const* d_in, const int* in_sizes, int n_in,
                              void* d_out, int out_size, void* d_ws,
                              size_t ws_size, hipStream_t stream) {
  (void)in_sizes; (void)n_in; (void)out_size;
  const float* xs   = (const float*)d_in[0];
  const float* icw0 = (const float*)d_in[1];
  const float* icb0 = (const float*)d_in[2];
  const float* icw1 = (const float*)d_in[3];
  const float* icb1 = (const float*)d_in[4];
  const float* icw2 = (const float*)d_in[5];
  const float* icb2 = (const float*)d_in[6];
  const float* vfw0 = (const float*)d_in[7];
  const float* vfb0 = (const float*)d_in[8];
  const float* vfw1 = (const float*)d_in[9];
  const float* vfb1 = (const float*)d_in[10];
  const float* vfw2 = (const float*)d_in[11];
  const float* vfb2 = (const float*)d_in[12];
  const float* row  = (const float*)d_in[13];
  const float* rob  = (const float*)d_in[14];
  float* ybuf = (float*)d_ws;  // 64*256*64 floats = 4 MB
  // transposed W2 lives after ybuf if workspace permits (4 MB + 512 KB)
  float* w2t = nullptr;
  if (ws_size >= (size_t)(4u * 1024u * 1024u + 512u * 1024u))
    w2t = (float*)d_ws + 1048576;

  // One-time variant arbitration: prefer zero scratch, then most VGPRs.
  static int pick = -1;
  if (pick < 0) {
    const void* fns[3] = {(const void*)cde_wpe, (const void*)cde_nvg,
                          (const void*)cde_base};
    long best = -0x7fffffffL;
    for (int i = 0; i < 3; ++i) {
      hipFuncAttributes fa{};
      if (hipFuncGetAttributes(&fa, fns[i]) != hipSuccess) continue;
      long score = -(long)fa.localSizeBytes * 4096 + (long)fa.numRegs;
      if (score > best) { best = score; pick = i; }
    }
    if (pick < 0) pick = 2;
  }

  if (w2t)
    hipLaunchKernelGGL(w2t_prep, dim3(512), dim3(256), 0, stream, vfw2, w2t);

  if (pick == 0)
    hipLaunchKernelGGL(cde_wpe, dim3(64), dim3(512), 0, stream,
                       xs, icw0, icb0, icw1, icb1, icw2, icb2,
                       vfw0, vfb0, vfw1, vfb1, vfw2, vfb2,
                       (const float*)w2t, ybuf);
  else if (pick == 1)
    hipLaunchKernelGGL(cde_nvg, dim3(64), dim3(512), 0, stream,
                       xs, icw0, icb0, icw1, icb1, icw2, icb2,
                       vfw0, vfb0, vfw1, vfb1, vfw2, vfb2,
                       (const float*)w2t, ybuf);
  else
    hipLaunchKernelGGL(cde_base, dim3(64), dim3(512), 0, stream,
                       xs, icw0, icb0, icw1, icb1, icw2, icb2,
                       vfw0, vfb0, vfw1, vfb1, vfw2, vfb2,
                       (const float*)w2t, ybuf);

  hipLaunchKernelGGL(readout, dim3(64), dim3(256), 0, stream,
                     ybuf, row, rob, (float*)d_out);
}

// Round 2
// 9955.293 us; speedup vs baseline: 1.4205x; 1.4205x over previous
//
#include <hip/hip_runtime.h>

// NeuralCDE: B=64,T=256,C=16,S=64,H=128. fp32 recursion (f16 decorrelates).
// R14: R13 post-mortem — all 3 attr variants gave VGPR=128 (cap is real, not
// attribute clobber); WRITE_SIZE 8.2->18.6MB + VALUBusy halved = scratch
// spill of the 144-float "pins" (they were never in registers; every k-phase
// re-read ~500B/thread from L2 scratch). Pivot: ZERO W2 pins. Honest budget:
// w0r(16)+w1r(32) pins + ~40 transient < 128. W2 cols 90..127 in LDS (152KB,
// unchanged); cols 0..89 STREAMED per k-phase from a one-time col-pair-major
// transpose w2p[P*2048+2r+(c&1)] in d_ws: one dwordx4/lane = rows r0,r1 x
// cols 2P,2P+1; wave = 1KB contiguous fully used. W2 is L2-resident (shared
// by 8 blocks/XCD): 360KB/block/stage -> ~1.0ms L2 roofline + ~1ms VALU.
// SIGNATURE next round: WRITE_SIZE ~8.2MB & FETCH ~5.4MB (scratch gone),
// VALUBusy 15-22%, dur 2.0-3.2ms. If >=4ms: L2 latency exposed -> pipeline
// deeper / add small named-var pin set.

typedef float float4v __attribute__((ext_vector_type(4)));
typedef float float2v __attribute__((ext_vector_type(2)));

__device__ __forceinline__ float dot4(float4v a, float4v b) {
  return a.x * b.x + a.y * b.y + a.z * b.z + a.w * b.w;
}

__device__ __forceinline__ float softplus_fast(float x) {
  float z = __expf(-fabsf(x));
  return fmaxf(x, 0.f) + __logf(1.f + z);
}

__device__ __forceinline__ float tanh_hw(float x) {
  float e = __expf(2.f * x);  // inf-safe
  return 1.f - 2.f * __builtin_amdgcn_rcpf(e + 1.f);
}

template <bool USEP>
__device__ __forceinline__ void cde_body(
    const float* __restrict__ xs,
    const float* __restrict__ icw0, const float* __restrict__ icb0,
    const float* __restrict__ icw1, const float* __restrict__ icb1,
    const float* __restrict__ icw2, const float* __restrict__ icb2,
    const float* __restrict__ vfw0, const float* __restrict__ vfb0,
    const float* __restrict__ vfw1, const float* __restrict__ vfb1,
    const float* __restrict__ vfw2, const float* __restrict__ vfb2,
    const float* __restrict__ w2p, float* __restrict__ ybuf) {
  constexpr float Ac[6][5] = {
      {0.f, 0.f, 0.f, 0.f, 0.f},
      {0.161f, 0.f, 0.f, 0.f, 0.f},
      {-0.008480655492356989f, 0.335480655492357f, 0.f, 0.f, 0.f},
      {2.8971530571054935f, -6.359448489975075f, 4.3622954328695815f, 0.f, 0.f},
      {5.325864828439257f, -11.748883564062828f, 7.4955393428898365f,
       -0.09249506636175525f, 0.f},
      {5.86145544294642f, -12.92096931784711f, 8.159367898576159f,
       -0.071584973281401f, -0.028269050394068383f}};
  constexpr float SCv[6] = {0.f, 0.161f, 0.327f, 0.9f, 0.9800255409045097f, 1.f};
  constexpr float BWv[6] = {0.09646076681806523f, 0.01f, 0.4798896504144996f,
                            1.379008574103742f, -3.290069515436081f,
                            2.324710524099774f};

  const int tid = threadIdx.x;
  const int w = tid >> 6, l = tid & 63;
  const int b = blockIdx.x;  // one block per batch element

  __shared__ float sW2t[38][1024];              // W2 cols 90..127 col-major
  __shared__ __align__(16) float sYtw[8][64];   // wave-private stage inputs
  __shared__ __align__(16) float sH1[128];
  __shared__ __align__(16) float sH2[128];
  __shared__ float sK[6][64];

  // ---- one-time: LDS W2 tail columns ----
  if (USEP) {
    for (int i = tid; i < 38 * 1024; i += 512) {
      int k = i >> 10, r = i & 1023;
      int c = 90 + k;
      sW2t[k][r] = w2p[(size_t)(c >> 1) * 2048 + r * 2 + (c & 1)];
    }
  } else {
    for (int i = tid; i < 38 * 1024; i += 512) {
      int k = i >> 10, r = i & 1023;
      sW2t[k][r] = vfw2[(size_t)r * 128 + 90 + k];
    }
  }

  const int r0 = tid * 2, r1 = r0 + 1;
  const int ii = tid >> 2, q4 = tid & 3;  // h1/h2: 4 lanes per output
  float w0r[16], w1r[32];
  {
    const float4v* p = (const float4v*)(vfw0 + (size_t)ii * 64 + q4 * 16);
#pragma unroll
    for (int kk = 0; kk < 4; ++kk) {
      float4v a = p[kk];
      w0r[4 * kk] = a.x; w0r[4 * kk + 1] = a.y;
      w0r[4 * kk + 2] = a.z; w0r[4 * kk + 3] = a.w;
    }
  }
  {
    const float4v* p = (const float4v*)(vfw1 + (size_t)ii * 128 + q4 * 32);
#pragma unroll
    for (int kk = 0; kk < 8; ++kk) {
      float4v a = p[kk];
      w1r[4 * kk] = a.x; w1r[4 * kk + 1] = a.y;
      w1r[4 * kk + 2] = a.z; w1r[4 * kk + 3] = a.w;
    }
  }
#pragma unroll
  for (int kk = 0; kk < 16; ++kk) asm volatile("" : "+v"(w0r[kk]));
#pragma unroll
  for (int kk = 0; kk < 32; ++kk) asm volatile("" : "+v"(w1r[kk]));

  const float b2r0 = vfb2[r0], b2r1 = vfb2[r1];
  const int c0 = (2 * l) & 15;  // even dx channel of row r0; r1 -> c0+1
  const float b0i = vfb0[ii], b1i = vfb1[ii];

  const float* Xb = xs + (size_t)b * 4096;
  float* yb = ybuf + (size_t)b * 16384;

  __syncthreads();

  // ---- initial condition MLP (one-time; sTA := sK[0..1], sTB := sH1) ----
  float* sTA = &sK[0][0];
  float* sTB = sH1;
  if (tid < 128) {
    float a = icb0[tid];
    const float* wr = icw0 + tid * 16;
#pragma unroll
    for (int k = 0; k < 16; ++k) a += wr[k] * Xb[k];
    sTA[tid] = softplus_fast(a);
  }
  __syncthreads();
  if (tid < 128) {
    float a = icb1[tid];
    const float* wr = icw1 + tid * 128;
    for (int k = 0; k < 128; ++k) a += wr[k] * sTA[k];
    sTB[tid] = softplus_fast(a);
  }
  __syncthreads();
  if (tid < 64) {
    float a = icb2[tid];
    const float* wr = icw2 + tid * 128;
    for (int k = 0; k < 128; ++k) a += wr[k] * sTB[k];
    sH2[tid] = a;  // temp broadcast slot
  }
  __syncthreads();
  float yreg = sH2[l];  // every wave holds y[l]
  if (w == 0) yb[l] = yreg;

  const float hstep = 1.f / 255.f;
  const float invh = 255.f;

#pragma unroll 1
  for (int t = 0; t < 255; ++t) {
    // per-lane x-channel pair (c0, c0+1): j-invariant dXdt basis in regs
    float2v xt = *(const float2v*)(Xb + t * 16 + c0);
    float2v xt1 = *(const float2v*)(Xb + (t + 1) * 16 + c0);
    float2v xtm = xt;
    if (t != 0) xtm = *(const float2v*)(Xb + (t - 1) * 16 + c0);
    const float u0 = xt.x - xt1.x, u1 = xt.y - xt1.y;       // (xi - xip1)
    const float dp0 = (xt1.x - xt.x) * invh;                 // dfull[t+1]
    const float dp1 = (xt1.y - xt.y) * invh;
    float di0 = (t == 0) ? dp0 : (xt.x - xtm.x) * invh;      // dfull[t]
    float di1 = (t == 0) ? dp1 : (xt.y - xtm.y) * invh;
#pragma unroll 1
    for (int j = 0; j < 6; ++j) {
      // ---- stage input y_j: every wave, per-lane, wave-private buffer ----
      {
        float yt = yreg;
#pragma unroll
        for (int m = 0; m < 5; ++m)
          if (m < j) yt += hstep * Ac[j][m] * sK[m][l];
        sYtw[w][l] = yt;
      }
      asm volatile("s_waitcnt lgkmcnt(0)" ::: "memory");  // in-wave only
      // ---- dXdt(sc_j) in registers ----
      const float sc = SCv[j], s2 = sc * sc;
      const float a1 = (6.f * s2 - 6.f * sc) * invh;
      const float a2 = 3.f * s2 - 4.f * sc + 1.f;
      const float a3 = 3.f * s2 - 2.f * sc;
      const float dx0 = a1 * u0 + a2 * di0 + a3 * dp0;
      const float dx1 = a1 * u1 + a2 * di1 + a3 * dp1;
      // ---- h1 = softplus(W0 @ y + b0) ----
      {
        const float4v* yv = (const float4v*)(&sYtw[w][0] + q4 * 16);
        float4v y0 = yv[0], y1 = yv[1], y2 = yv[2], y3 = yv[3];
        float s = w0r[0] * y0.x + w0r[1] * y0.y + w0r[2] * y0.z +
                  w0r[3] * y0.w + w0r[4] * y1.x + w0r[5] * y1.y +
                  w0r[6] * y1.z + w0r[7] * y1.w + w0r[8] * y2.x +
                  w0r[9] * y2.y + w0r[10] * y2.z + w0r[11] * y2.w +
                  w0r[12] * y3.x + w0r[13] * y3.y + w0r[14] * y3.z +
                  w0r[15] * y3.w;
        s += __shfl_xor(s, 1);
        s += __shfl_xor(s, 2);
        if (q4 == 0) sH1[ii] = softplus_fast(s + b0i);
      }
      __syncthreads();
      // ---- h2 = softplus(W1 @ h1 + b1) ----
      {
        const float4v* hv = (const float4v*)(sH1 + q4 * 32);
        float s = 0.f;
#pragma unroll
        for (int kk = 0; kk < 8; ++kk) {
          float4v h = hv[kk];
          s += w1r[4 * kk] * h.x + w1r[4 * kk + 1] * h.y +
               w1r[4 * kk + 2] * h.z + w1r[4 * kk + 3] * h.w;
        }
        s += __shfl_xor(s, 1);
        s += __shfl_xor(s, 2);
        if (q4 == 0) sH2[ii] = softplus_fast(s + b1i);
      }
      __syncthreads();
      // ---- k: rows r0,r1 of A = tanh(W2 h2 + b2), * dx, reduce over c ----
      {
        float s0 = 0.f, s1 = 0.f;
        if (USEP) {
          // streamed cols 0..89 from col-pair-major w2p; loads indep of h2
          const float* pb = w2p + (size_t)r0 * 2;
#pragma unroll
          for (int q = 0; q < 22; ++q) {  // cols 0..87
            float4v h = *(const float4v*)(sH2 + 4 * q);
            float4v wA = *(const float4v*)(pb + (size_t)(2 * q) * 2048);
            float4v wB = *(const float4v*)(pb + (size_t)(2 * q + 1) * 2048);
            s0 += wA.x * h.x + wA.y * h.y + wB.x * h.z + wB.y * h.w;
            s1 += wA.z * h.x + wA.w * h.y + wB.z * h.z + wB.w * h.w;
          }
          {  // pair 44: cols 88,89
            float2v h = *(const float2v*)(sH2 + 88);
            float4v wA = *(const float4v*)(pb + (size_t)44 * 2048);
            s0 += wA.x * h.x + wA.y * h.y;
            s1 += wA.z * h.x + wA.w * h.y;
          }
        } else {
          // fallback: row-major stream straight from vfw2
          const float* wr0 = vfw2 + (size_t)r0 * 128;
          const float* wr1 = vfw2 + (size_t)r1 * 128;
          const float4v* hv = (const float4v*)sH2;
#pragma unroll
          for (int kk = 0; kk < 22; ++kk) {
            float4v h = hv[kk];
            float4v a = ((const float4v*)wr0)[kk];
            float4v c = ((const float4v*)wr1)[kk];
            s0 += dot4(a, h);
            s1 += dot4(c, h);
          }
          {
            float2v h = *(const float2v*)(sH2 + 88);
            s0 += wr0[88] * h.x + wr0[89] * h.y;
            s1 += wr1[88] * h.x + wr1[89] * h.y;
          }
        }
#pragma unroll 4
        for (int k2 = 0; k2 < 19; ++k2) {  // LDS cols 90..127, pairwise
          float2v hk = *(const float2v*)(sH2 + 90 + 2 * k2);
          float2v wlo = *(const float2v*)&sW2t[2 * k2][r0];
          float2v whi = *(const float2v*)&sW2t[2 * k2 + 1][r0];
          s0 += wlo.x * hk.x + whi.x * hk.y;
          s1 += wlo.y * hk.x + whi.y * hk.y;
        }
        float f = tanh_hw(s0 + b2r0) * dx0 + tanh_hw(s1 + b2r1) * dx1;
        f += __shfl_xor(f, 1);
        f += __shfl_xor(f, 2);
        f += __shfl_xor(f, 4);
        if ((tid & 7) == 0) sK[j][tid >> 3] = f;
      }
      __syncthreads();
    }
    // ---- y_{t+1}: every wave redundantly; wave0 dumps the state ----
    {
      float yn = yreg;
#pragma unroll
      for (int m = 0; m < 6; ++m) yn += hstep * BWv[m] * sK[m][l];
      yreg = yn;
      if (w == 0) yb[(size_t)(t + 1) * 64 + l] = yn;
    }
  }
}

#define CDE_ARGS_DECL \
    const float* __restrict__ xs, \
    const float* __restrict__ icw0, const float* __restrict__ icb0, \
    const float* __restrict__ icw1, const float* __restrict__ icb1, \
    const float* __restrict__ icw2, const float* __restrict__ icb2, \
    const float* __restrict__ vfw0, const float* __restrict__ vfb0, \
    const float* __restrict__ vfw1, const float* __restrict__ vfb1, \
    const float* __restrict__ vfw2, const float* __restrict__ vfb2, \
    const float* __restrict__ w2p, float* __restrict__ ybuf
#define CDE_ARGS_PASS \
    xs, icw0, icb0, icw1, icb1, icw2, icb2, vfw0, vfb0, vfw1, vfb1, vfw2, \
    vfb2, w2p, ybuf

// R0-proven attribute combo (compiles to 128 VGPR, no surprises).
__global__ __attribute__((amdgpu_waves_per_eu(2, 2)))
__launch_bounds__(512, 1) void cde_p(CDE_ARGS_DECL) {
  cde_body<true>(CDE_ARGS_PASS);
}
__global__ __attribute__((amdgpu_waves_per_eu(2, 2)))
__launch_bounds__(512, 1) void cde_rm(CDE_ARGS_DECL) {
  cde_body<false>(CDE_ARGS_PASS);
}

// One-time W2 repack, col-pair-major: w2p[(c>>1)*2048 + 2r + (c&1)] = W2[r][c]
__global__ __launch_bounds__(256) void w2p_prep(const float* __restrict__ w2,
                                                float* __restrict__ out) {
  int i = blockIdx.x * 256 + threadIdx.x;  // [0, 131072)
  int r = i >> 7, c = i & 127;
  out[(size_t)(c >> 1) * 2048 + r * 2 + (c & 1)] = w2[i];
}

// Parallel readout: one thread per (b,t): out6 = y @ ro^T + rob, 6D->SO(3).
__global__ __launch_bounds__(256) void readout(
    const float* __restrict__ ybuf, const float* __restrict__ row,
    const float* __restrict__ rob, float* __restrict__ out) {
  int idx = blockIdx.x * blockDim.x + threadIdx.x;  // b*256+t
  const float* y = ybuf + (size_t)idx * 64;
  float p[6];
#pragma unroll
  for (int o = 0; o < 6; ++o) {
    const float4v* rr = (const float4v*)(row + o * 64);
    const float4v* yv = (const float4v*)y;
    float s = 0.f;
#pragma unroll
    for (int k = 0; k < 16; ++k) s += dot4(rr[k], yv[k]);
    p[o] = s + rob[o];
  }
  float a1x = p[0], a1y = p[1], a1z = p[2];
  float a2x = p[3], a2y = p[4], a2z = p[5];
  float n1 = rsqrtf(a1x * a1x + a1y * a1y + a1z * a1z);
  float b1x = a1x * n1, b1y = a1y * n1, b1z = a1z * n1;
  float d = b1x * a2x + b1y * a2y + b1z * a2z;
  float px = a2x - d * b1x, py = a2y - d * b1y, pz = a2z - d * b1z;
  float n2 = rsqrtf(px * px + py * py + pz * pz);
  float b2x = px * n2, b2y = py * n2, b2z = pz * n2;
  float b3x = b1y * b2z - b1z * b2y;
  float b3y = b1z * b2x - b1x * b2z;
  float b3z = b1x * b2y - b1y * b2x;
  float* o = out + (size_t)idx * 9;
  o[0] = b1x; o[1] = b2x; o[2] = b3x;
  o[3] = b1y; o[4] = b2y; o[5] = b3y;
  o[6] = b1z; o[7] = b2z; o[8] = b3z;
}

extern "C" void kernel_launch(void* const* d_in, const int* in_sizes, int n_in,
                              void* d_out, int out_size, void* d_ws,
                              size_t ws_size, hipStream_t stream) {
  (void)in_sizes; (void)n_in; (void)out_size;
  const float* xs   = (const float*)d_in[0];
  const float* icw0 = (const float*)d_in[1];
  const float* icb0 = (const float*)d_in[2];
  const float* icw1 = (const float*)d_in[3];
  const float* icb1 = (const float*)d_in[4];
  const float* icw2 = (const float*)d_in[5];
  const float* icb2 = (const float*)d_in[6];
  const float* vfw0 = (const float*)d_in[7];
  const float* vfb0 = (const float*)d_in[8];
  const float* vfw1 = (const float*)d_in[9];
  const float* vfb1 = (const float*)d_in[10];
  const float* vfw2 = (const float*)d_in[11];
  const float* vfb2 = (const float*)d_in[12];
  const float* row  = (const float*)d_in[13];
  const float* rob  = (const float*)d_in[14];
  float* ybuf = (float*)d_ws;  // 64*256*64 floats = 4 MB
  // repacked W2 lives after ybuf if workspace permits (4 MB + 512 KB)
  float* w2p = nullptr;
  if (ws_size >= (size_t)(4u * 1024u * 1024u + 512u * 1024u))
    w2p = (float*)d_ws + 1048576;

  if (w2p) {
    hipLaunchKernelGGL(w2p_prep, dim3(512), dim3(256), 0, stream, vfw2, w2p);
    hipLaunchKernelGGL(cde_p, dim3(64), dim3(512), 0, stream,
                       xs, icw0, icb0, icw1, icb1, icw2, icb2,
                       vfw0, vfb0, vfw1, vfb1, vfw2, vfb2,
                       (const float*)w2p, ybuf);
  } else {
    hipLaunchKernelGGL(cde_rm, dim3(64), dim3(512), 0, stream,
                       xs, icw0, icb0, icw1, icb1, icw2, icb2,
                       vfw0, vfb0, vfw1, vfb1, vfw2, vfb2,
                       (const float*)nullptr, ybuf);
  }

  hipLaunchKernelGGL(readout, dim3(64), dim3(256), 0, stream,
                     ybuf, row, rob, (float*)d_out);
}

// Round 3
// 8863.197 us; speedup vs baseline: 1.5955x; 1.1232x over previous
//
#include <hip/hip_runtime.h>

// NeuralCDE: B=64,T=256,C=16,S=64,H=128. fp32 recursion (f16 decorrelates).
// R15: R14 post-mortem — streaming 90 cols was L2-BW-bound (delta = 127
// GB/s/CU ~= per-CU L2 limit). R0's pins were real (256-reg unified-file
// budget at wpe(2,2)), its 6.5ms was ~70% latency stall (2 waves/SIMD, 3
// barriers, 7 dependent shfls). Pivot: 1024 threads (16 waves, 4/SIMD =
// 2x latency hiding, reg file exactly full at 128/thread). One W2 row per
// thread: pins 72+8+16=96 floats -> genuinely fits 128 VGPRs. Stream only
// cols 72..89 (73KB/stage/CU, L2-safe) as coalesced float2 from w2p repack;
// LDS tail cols 90..127 pair-packed (linear one-time copy from w2p).
// SIGNATURE next round: dur 2.8-4.0ms, VALUBusy 12-16%, WRITE ~8.2MB,
// FETCH ~5.4MB. If >=5ms: latency still dominant -> merge h1/h2, cut
// barriers next.

typedef float float4v __attribute__((ext_vector_type(4)));
typedef float float2v __attribute__((ext_vector_type(2)));

__device__ __forceinline__ float dot4(float4v a, float4v b) {
  return a.x * b.x + a.y * b.y + a.z * b.z + a.w * b.w;
}

__device__ __forceinline__ float softplus_fast(float x) {
  float z = __expf(-fabsf(x));
  return fmaxf(x, 0.f) + __logf(1.f + z);
}

__device__ __forceinline__ float tanh_hw(float x) {
  float e = __expf(2.f * x);  // inf-safe
  return 1.f - 2.f * __builtin_amdgcn_rcpf(e + 1.f);
}

template <bool USEP>
__device__ __forceinline__ void cde_body(
    const float* __restrict__ xs,
    const float* __restrict__ icw0, const float* __restrict__ icb0,
    const float* __restrict__ icw1, const float* __restrict__ icb1,
    const float* __restrict__ icw2, const float* __restrict__ icb2,
    const float* __restrict__ vfw0, const float* __restrict__ vfb0,
    const float* __restrict__ vfw1, const float* __restrict__ vfb1,
    const float* __restrict__ vfw2, const float* __restrict__ vfb2,
    const float* __restrict__ w2p, float* __restrict__ ybuf) {
  constexpr float Ac[6][5] = {
      {0.f, 0.f, 0.f, 0.f, 0.f},
      {0.161f, 0.f, 0.f, 0.f, 0.f},
      {-0.008480655492356989f, 0.335480655492357f, 0.f, 0.f, 0.f},
      {2.8971530571054935f, -6.359448489975075f, 4.3622954328695815f, 0.f, 0.f},
      {5.325864828439257f, -11.748883564062828f, 7.4955393428898365f,
       -0.09249506636175525f, 0.f},
      {5.86145544294642f, -12.92096931784711f, 8.159367898576159f,
       -0.071584973281401f, -0.028269050394068383f}};
  constexpr float SCv[6] = {0.f, 0.161f, 0.327f, 0.9f, 0.9800255409045097f, 1.f};
  constexpr float BWv[6] = {0.09646076681806523f, 0.01f, 0.4798896504144996f,
                            1.379008574103742f, -3.290069515436081f,
                            2.324710524099774f};

  const int tid = threadIdx.x;             // 0..1023
  const int w = tid >> 6, l = tid & 63;
  const int b = blockIdx.x;                // one block per batch element

  // LDS: W2 cols 90..127 pair-packed: sW2t[P*2048 + 2r + e] = W2[r][90+2P+e]
  __shared__ float sW2t[19 * 2048];             // 152 KB
  __shared__ __align__(16) float sYtw[16][64];  // wave-private stage inputs
  __shared__ __align__(16) float sH1[128];
  __shared__ __align__(16) float sH2[128];
  __shared__ float sK[6][64];

  // ---- one-time: LDS W2 tail (linear copy when repack exists) ----
  if (USEP) {
    const float* src = w2p + (size_t)45 * 2048;  // pairs 45..63 = cols 90..127
    for (int i = tid; i < 19 * 1024; i += 1024) {
      ((float2v*)sW2t)[i] = ((const float2v*)src)[i];
    }
  } else {
    for (int i = tid; i < 19 * 2048; i += 1024) {
      int P = i >> 11, rem = i & 2047, r = rem >> 1, e = rem & 1;
      sW2t[i] = vfw2[(size_t)r * 128 + 90 + 2 * P + e];
    }
  }

  // ---- one-time: pinned weights (one W2 row per thread, cols 0..71) ----
  const int r = tid;                       // W2 row
  float w2a[72];
  if (USEP) {
#pragma unroll
    for (int q = 0; q < 36; ++q) {
      float2v v = *(const float2v*)(w2p + (size_t)q * 2048 + 2 * r);
      w2a[2 * q] = v.x; w2a[2 * q + 1] = v.y;
    }
  } else {
    const float4v* p0 = (const float4v*)(vfw2 + (size_t)r * 128);
#pragma unroll
    for (int kk = 0; kk < 18; ++kk) {
      float4v a = p0[kk];
      w2a[4 * kk + 0] = a.x; w2a[4 * kk + 1] = a.y;
      w2a[4 * kk + 2] = a.z; w2a[4 * kk + 3] = a.w;
    }
  }
#pragma unroll
  for (int kk = 0; kk < 72; ++kk) asm volatile("" : "+v"(w2a[kk]));

  const int ii = tid >> 3, q8 = tid & 7;   // h1/h2: 8 lanes per output
  float w0r[8], w1r[16];
  {
    const float4v* p = (const float4v*)(vfw0 + (size_t)ii * 64 + q8 * 8);
    float4v a = p[0], c = p[1];
    w0r[0] = a.x; w0r[1] = a.y; w0r[2] = a.z; w0r[3] = a.w;
    w0r[4] = c.x; w0r[5] = c.y; w0r[6] = c.z; w0r[7] = c.w;
  }
  {
    const float4v* p = (const float4v*)(vfw1 + (size_t)ii * 128 + q8 * 16);
#pragma unroll
    for (int kk = 0; kk < 4; ++kk) {
      float4v a = p[kk];
      w1r[4 * kk] = a.x; w1r[4 * kk + 1] = a.y;
      w1r[4 * kk + 2] = a.z; w1r[4 * kk + 3] = a.w;
    }
  }
#pragma unroll
  for (int kk = 0; kk < 8; ++kk) asm volatile("" : "+v"(w0r[kk]));
#pragma unroll
  for (int kk = 0; kk < 16; ++kk) asm volatile("" : "+v"(w1r[kk]));

  const float b2r = vfb2[r];
  const int c = tid & 15;                  // dx channel of this row
  const float b0i = vfb0[ii], b1i = vfb1[ii];

  const float* Xb = xs + (size_t)b * 4096;
  float* yb = ybuf + (size_t)b * 16384;

  __syncthreads();

  // ---- initial condition MLP (one-time; sTA := sK[0..1], sTB := sH1) ----
  float* sTA = &sK[0][0];
  float* sTB = sH1;
  if (tid < 128) {
    float a = icb0[tid];
    const float* wr = icw0 + tid * 16;
#pragma unroll
    for (int k = 0; k < 16; ++k) a += wr[k] * Xb[k];
    sTA[tid] = softplus_fast(a);
  }
  __syncthreads();
  if (tid < 128) {
    float a = icb1[tid];
    const float* wr = icw1 + tid * 128;
    for (int k = 0; k < 128; ++k) a += wr[k] * sTA[k];
    sTB[tid] = softplus_fast(a);
  }
  __syncthreads();
  if (tid < 64) {
    float a = icb2[tid];
    const float* wr = icw2 + tid * 128;
    for (int k = 0; k < 128; ++k) a += wr[k] * sTB[k];
    sH2[tid] = a;  // temp broadcast slot
  }
  __syncthreads();
  float yreg = sH2[l];  // every wave holds y[l]
  if (w == 0) yb[l] = yreg;

  const float hstep = 1.f / 255.f;
  const float invh = 255.f;

#pragma unroll 1
  for (int t = 0; t < 255; ++t) {
    // per-lane x-channel c: j-invariant dXdt basis in regs
    float xt = Xb[t * 16 + c];
    float xt1 = Xb[(t + 1) * 16 + c];
    float xtm = (t != 0) ? Xb[(t - 1) * 16 + c] : xt;
    const float u0 = xt - xt1;                        // (xi - xip1)
    const float dp0 = (xt1 - xt) * invh;              // dfull[t+1]
    const float di0 = (t == 0) ? dp0 : (xt - xtm) * invh;  // dfull[t]
#pragma unroll 1
    for (int j = 0; j < 6; ++j) {
      // ---- streamed W2 cols 72..89 (pairs 36..44), consumed in k-phase ----
      float st[18];
      if (USEP) {
        const float* pb = w2p + 2 * r;
#pragma unroll
        for (int q = 0; q < 9; ++q) {
          float2v v = *(const float2v*)(pb + (size_t)(36 + q) * 2048);
          st[2 * q] = v.x; st[2 * q + 1] = v.y;
        }
      } else {
        const float* wr0 = vfw2 + (size_t)r * 128 + 72;
#pragma unroll
        for (int q = 0; q < 4; ++q) {
          float4v v = *(const float4v*)(wr0 + 4 * q);
          st[4 * q] = v.x; st[4 * q + 1] = v.y;
          st[4 * q + 2] = v.z; st[4 * q + 3] = v.w;
        }
        float2v v = *(const float2v*)(wr0 + 16);
        st[16] = v.x; st[17] = v.y;
      }
      // ---- stage input y_j: every wave, per-lane, wave-private buffer ----
      {
        float yt = yreg;
#pragma unroll
        for (int m = 0; m < 5; ++m)
          if (m < j) yt += hstep * Ac[j][m] * sK[m][l];
        sYtw[w][l] = yt;
      }
      asm volatile("s_waitcnt lgkmcnt(0)" ::: "memory");  // in-wave only
      // ---- dXdt(sc_j) in registers ----
      const float sc = SCv[j], s2 = sc * sc;
      const float a1 = (6.f * s2 - 6.f * sc) * invh;
      const float a2 = 3.f * s2 - 4.f * sc + 1.f;
      const float a3 = 3.f * s2 - 2.f * sc;
      const float dx0 = a1 * u0 + a2 * di0 + a3 * dp0;
      // ---- h1 = softplus(W0 @ y + b0): 8 lanes per output ----
      {
        const float4v* yv = (const float4v*)(&sYtw[w][0] + q8 * 8);
        float4v y0 = yv[0], y1 = yv[1];
        float s = w0r[0] * y0.x + w0r[1] * y0.y + w0r[2] * y0.z +
                  w0r[3] * y0.w + w0r[4] * y1.x + w0r[5] * y1.y +
                  w0r[6] * y1.z + w0r[7] * y1.w;
        s += __shfl_xor(s, 1);
        s += __shfl_xor(s, 2);
        s += __shfl_xor(s, 4);
        if (q8 == 0) sH1[ii] = softplus_fast(s + b0i);
      }
      __syncthreads();
      // ---- h2 = softplus(W1 @ h1 + b1): 8 lanes per output ----
      {
        const float4v* hv = (const float4v*)(sH1 + q8 * 16);
        float s = 0.f;
#pragma unroll
        for (int kk = 0; kk < 4; ++kk) {
          float4v h = hv[kk];
          s += w1r[4 * kk] * h.x + w1r[4 * kk + 1] * h.y +
               w1r[4 * kk + 2] * h.z + w1r[4 * kk + 3] * h.w;
        }
        s += __shfl_xor(s, 1);
        s += __shfl_xor(s, 2);
        s += __shfl_xor(s, 4);
        if (q8 == 0) sH2[ii] = softplus_fast(s + b1i);
      }
      __syncthreads();
      // ---- k: row r of A = tanh(W2 h2 + b2), * dx, reduce over c ----
      {
        float s0 = 0.f;
        const float4v* hv = (const float4v*)sH2;
#pragma unroll
        for (int kk = 0; kk < 18; ++kk) {  // pinned cols 0..71
          float4v h = hv[kk];
          s0 += w2a[4 * kk] * h.x + w2a[4 * kk + 1] * h.y +
                w2a[4 * kk + 2] * h.z + w2a[4 * kk + 3] * h.w;
        }
        {  // streamed cols 72..89
          float4v h0 = hv[18], h1 = hv[19], h2f = hv[20], h3 = hv[21];
          float2v h4 = *(const float2v*)(sH2 + 88);
          s0 += st[0] * h0.x + st[1] * h0.y + st[2] * h0.z + st[3] * h0.w +
                st[4] * h1.x + st[5] * h1.y + st[6] * h1.z + st[7] * h1.w +
                st[8] * h2f.x + st[9] * h2f.y + st[10] * h2f.z +
                st[11] * h2f.w + st[12] * h3.x + st[13] * h3.y +
                st[14] * h3.z + st[15] * h3.w + st[16] * h4.x + st[17] * h4.y;
        }
#pragma unroll 4
        for (int P = 0; P < 19; ++P) {  // LDS cols 90..127, pair-packed
          float2v hk = *(const float2v*)(sH2 + 90 + 2 * P);
          float2v wp = *(const float2v*)&sW2t[P * 2048 + 2 * r];
          s0 += wp.x * hk.x + wp.y * hk.y;
        }
        float f = tanh_hw(s0 + b2r) * dx0;
        f += __shfl_xor(f, 1);
        f += __shfl_xor(f, 2);
        f += __shfl_xor(f, 4);
        f += __shfl_xor(f, 8);
        if ((tid & 15) == 0) sK[j][tid >> 4] = f;
      }
      __syncthreads();
    }
    // ---- y_{t+1}: every wave redundantly; wave0 dumps the state ----
    {
      float yn = yreg;
#pragma unroll
      for (int m = 0; m < 6; ++m) yn += hstep * BWv[m] * sK[m][l];
      yreg = yn;
      if (w == 0) yb[(size_t)(t + 1) * 64 + l] = yn;
    }
  }
}

#define CDE_ARGS_DECL \
    const float* __restrict__ xs, \
    const float* __restrict__ icw0, const float* __restrict__ icb0, \
    const float* __restrict__ icw1, const float* __restrict__ icb1, \
    const float* __restrict__ icw2, const float* __restrict__ icb2, \
    const float* __restrict__ vfw0, const float* __restrict__ vfb0, \
    const float* __restrict__ vfw1, const float* __restrict__ vfb1, \
    const float* __restrict__ vfw2, const float* __restrict__ vfb2, \
    const float* __restrict__ w2p, float* __restrict__ ybuf
#define CDE_ARGS_PASS \
    xs, icw0, icb0, icw1, icb1, icw2, icb2, vfw0, vfb0, vfw1, vfb1, vfw2, \
    vfb2, w2p, ybuf

// 1024 threads, 1 WG/CU (16 waves = 4/SIMD, 128 VGPR/thread = full file).
__global__ __launch_bounds__(1024, 1) void cde_p(CDE_ARGS_DECL) {
  cde_body<true>(CDE_ARGS_PASS);
}
__global__ __launch_bounds__(1024, 1) void cde_rm(CDE_ARGS_DECL) {
  cde_body<false>(CDE_ARGS_PASS);
}

// One-time W2 repack, col-pair-major: w2p[(c>>1)*2048 + 2r + (c&1)] = W2[r][c]
__global__ __launch_bounds__(256) void w2p_prep(const float* __restrict__ w2,
                                                float* __restrict__ out) {
  int i = blockIdx.x * 256 + threadIdx.x;  // [0, 131072)
  int r = i >> 7, c = i & 127;
  out[(size_t)(c >> 1) * 2048 + r * 2 + (c & 1)] = w2[i];
}

// Parallel readout: one thread per (b,t): out6 = y @ ro^T + rob, 6D->SO(3).
__global__ __launch_bounds__(256) void readout(
    const float* __restrict__ ybuf, const float* __restrict__ row,
    const float* __restrict__ rob, float* __restrict__ out) {
  int idx = blockIdx.x * blockDim.x + threadIdx.x;  // b*256+t
  const float* y = ybuf + (size_t)idx * 64;
  float p[6];
#pragma unroll
  for (int o = 0; o < 6; ++o) {
    const float4v* rr = (const float4v*)(row + o * 64);
    const float4v* yv = (const float4v*)y;
    float s = 0.f;
#pragma unroll
    for (int k = 0; k < 16; ++k) s += dot4(rr[k], yv[k]);
    p[o] = s + rob[o];
  }
  float a1x = p[0], a1y = p[1], a1z = p[2];
  float a2x = p[3], a2y = p[4], a2z = p[5];
  float n1 = rsqrtf(a1x * a1x + a1y * a1y + a1z * a1z);
  float b1x = a1x * n1, b1y = a1y * n1, b1z = a1z * n1;
  float d = b1x * a2x + b1y * a2y + b1z * a2z;
  float px = a2x - d * b1x, py = a2y - d * b1y, pz = a2z - d * b1z;
  float n2 = rsqrtf(px * px + py * py + pz * pz);
  float b2x = px * n2, b2y = py * n2, b2z = pz * n2;
  float b3x = b1y * b2z - b1z * b2y;
  float b3y = b1z * b2x - b1x * b2z;
  float b3z = b1x * b2y - b1y * b2x;
  float* o = out + (size_t)idx * 9;
  o[0] = b1x; o[1] = b2x; o[2] = b3x;
  o[3] = b1y; o[4] = b2y; o[5] = b3y;
  o[6] = b1z; o[7] = b2z; o[8] = b3z;
}

extern "C" void kernel_launch(void* const* d_in, const int* in_sizes, int n_in,
                              void* d_out, int out_size, void* d_ws,
                              size_t ws_size, hipStream_t stream) {
  (void)in_sizes; (void)n_in; (void)out_size;
  const float* xs   = (const float*)d_in[0];
  const float* icw0 = (const float*)d_in[1];
  const float* icb0 = (const float*)d_in[2];
  const float* icw1 = (const float*)d_in[3];
  const float* icb1 = (const float*)d_in[4];
  const float* icw2 = (const float*)d_in[5];
  const float* icb2 = (const float*)d_in[6];
  const float* vfw0 = (const float*)d_in[7];
  const float* vfb0 = (const float*)d_in[8];
  const float* vfw1 = (const float*)d_in[9];
  const float* vfb1 = (const float*)d_in[10];
  const float* vfw2 = (const float*)d_in[11];
  const float* vfb2 = (const float*)d_in[12];
  const float* row  = (const float*)d_in[13];
  const float* rob  = (const float*)d_in[14];
  float* ybuf = (float*)d_ws;  // 64*256*64 floats = 4 MB
  // repacked W2 lives after ybuf if workspace permits (4 MB + 512 KB)
  float* w2p = nullptr;
  if (ws_size >= (size_t)(4u * 1024u * 1024u + 512u * 1024u))
    w2p = (float*)d_ws + 1048576;

  if (w2p) {
    hipLaunchKernelGGL(w2p_prep, dim3(512), dim3(256), 0, stream, vfw2, w2p);
    hipLaunchKernelGGL(cde_p, dim3(64), dim3(1024), 0, stream,
                       xs, icw0, icb0, icw1, icb1, icw2, icb2,
                       vfw0, vfb0, vfw1, vfb1, vfw2, vfb2,
                       (const float*)w2p, ybuf);
  } else {
    hipLaunchKernelGGL(cde_rm, dim3(64), dim3(1024), 0, stream,
                       xs, icw0, icb0, icw1, icb1, icw2, icb2,
                       vfw0, vfb0, vfw1, vfb1, vfw2, vfb2,
                       (const float*)nullptr, ybuf);
  }

  hipLaunchKernelGGL(readout, dim3(64), dim3(256), 0, stream,
                     ybuf, row, rob, (float*)d_out);
}